// Round 7
// baseline (175.427 us; speedup 1.0000x reference)
//
#include <hip/hip_runtime.h>
#include <math.h>

#define DIM 64
#define KC 32
#define NPTS 32768
#define LOG_2PI 1.8378770664093453f
#define C0 (-58.0f)   // fixed logsumexp reference: logp <= -58.81 always (logdet>=0, logw<=0)
#define ST 66         // prep LDS row stride (words)

typedef __attribute__((ext_vector_type(8))) short short8;
typedef __attribute__((ext_vector_type(4))) float float4v;

__device__ __forceinline__ unsigned short f2bf(float f) {
    unsigned u = __float_as_uint(f);
    u += 0x7FFFu + ((u >> 16) & 1u);   // RNE
    return (unsigned short)(u >> 16);
}

__device__ __forceinline__ float rdlane(float v, int l) {
    return __int_as_float(__builtin_amdgcn_readlane(__float_as_int(v), l));
}

// DPP adds (VALU pipe, not LDS): xor1, xor2 via quad_perm; xor4/xor8-equivalent
// via half-row / row mirrors (exact on data already uniform at the finer level).
template <int CTRL>
__device__ __forceinline__ float dpp_add(float x) {
    int t = __builtin_amdgcn_mov_dpp(__float_as_int(x), CTRL, 0xF, 0xF, true);
    return x + __int_as_float(t);
}
__device__ __forceinline__ float sum16(float x) {   // sum within each 16-lane row
    x = dpp_add<0xB1>(x);    // quad_perm [1,0,3,2]  : xor 1
    x = dpp_add<0x4E>(x);    // quad_perm [2,3,0,1]  : xor 2
    x = dpp_add<0x141>(x);   // row_half_mirror      : xor 4 on quad-uniform
    x = dpp_add<0x140>(x);   // row_mirror           : xor 8 on 8-uniform
    return x;
}

// ============================================================================
// Prep: one block (256 thr) per component k; 32 blocks.
// P1: Sigma = I + tril(L)tril(L)^T in LDS (4 waves, 16 cols each).
// P2 (wave 0): ROTATED-REGISTER merged Cholesky + inverse. Lane r holds the
//   trailing matrix row in S[64] with the invariant S[j] = col (c+j); the
//   active column is always S[0] (static index), readlane uses a runtime
//   SGPR lane index, and one fma both updates and rotates:
//     S[j-1] = fma(-myc, s, S[j]),  A[j-1] = fma(yc, s, A[j])
//   where s = readlane(myc, c+j) is shared by chol and inverse. Lanes r<c
//   hold junk that never escapes (readlane always targets lanes >= c+1);
//   Y = M rows come out exact at ALL lanes (zeros above diag automatic).
//   Zero LDS traffic in the loop except one ds_write (Y row) per step.
// P3: q = M mu; emit 12 MFMA B-fragments + cstC[k] = cst_k - C0.
// ============================================================================
__global__ __launch_bounds__(256, 1) void prep_kernel(
    const float* __restrict__ L, const float* __restrict__ mu,
    const float* __restrict__ w, short* __restrict__ Bpack,
    float* __restrict__ cstC, int* __restrict__ counter)
{
    const int k = blockIdx.x;
    const int t = threadIdx.x;
    const int wv = t >> 6;
    const int ln = t & 63;
    __shared__ float Llds[DIM * ST];
    __shared__ float Sig[DIM * ST];
    __shared__ float Ylds[DIM * ST];   // Ylds[i*ST + j] = M[i][j]
    __shared__ float qlds[DIM];

    if (k == 0 && t == 0) *counter = 0;   // for main's folded final reduction

    // ---- P0: load tril(L), zeros above diag
    for (int idx = t; idx < DIM * DIM; idx += 256) {
        int r = idx >> 6, c = idx & 63;
        float v = L[(size_t)k * DIM * DIM + idx];
        Llds[r * ST + c] = (c <= r) ? v : 0.f;
    }
    __syncthreads();

    // ---- P1: Sigma[ln][j], 16 cols per wave (tril zeros -> full sums exact)
    {
        float Lr[DIM];
        const float2* lp = (const float2*)(Llds + ln * ST);
#pragma unroll
        for (int p = 0; p < 32; ++p) {
            float2 v = lp[p];
            Lr[2 * p] = v.x; Lr[2 * p + 1] = v.y;
        }
#pragma unroll 1
        for (int jj = 0; jj < 16; ++jj) {
            const int j = wv * 16 + jj;
            const float2* up = (const float2*)(Llds + j * ST);
            float a0 = 0.f, a1 = 0.f, a2 = 0.f, a3 = 0.f;
#pragma unroll
            for (int p = 0; p < 32; p += 2) {
                float2 u0 = up[p], u1 = up[p + 1];
                a0 = fmaf(Lr[2 * p], u0.x, a0);
                a1 = fmaf(Lr[2 * p + 1], u0.y, a1);
                a2 = fmaf(Lr[2 * p + 2], u1.x, a2);
                a3 = fmaf(Lr[2 * p + 3], u1.y, a3);
            }
            float s = (a0 + a1) + (a2 + a3);
            if (j == ln) s += 1.f;
            Sig[ln * ST + j] = s;
        }
    }
    __syncthreads();

    // ---- P2: rotated-register merged Cholesky + inverse (wave 0)
    if (wv == 0) {
        float S[DIM], A[DIM];
        {
            const float2* sp = (const float2*)(Sig + ln * ST);
#pragma unroll
            for (int p = 0; p < 32; ++p) {
                float2 v = sp[p];
                S[2 * p] = v.x; S[2 * p + 1] = v.y;
            }
        }
#pragma unroll
        for (int j = 0; j < DIM; ++j) A[j] = 0.f;

        float ld2 = 0.f;   // sum log(d_c^2) = logdet (uniform)
#pragma unroll 1
        for (int c = 0; c < DIM; ++c) {
            float s0v = S[0];
            float d2 = rdlane(s0v, c);            // trailing diagonal (lane c valid)
            ld2 += __logf(d2);
            float rd = __builtin_amdgcn_rsqf(d2); // = 1/C[c][c]
            float myc = s0v * rd;                 // C[r][c] (junk r<c, never read)
            float yc = (((ln == c) ? 1.f : 0.f) - A[0]) * rd;  // M[c][ln], exact all lanes
            Ylds[c * ST + ln] = yc;
#pragma unroll
            for (int j = 1; j < DIM; ++j) {
                float s = rdlane(myc, (c + j) & 63);   // C[c+j][c] (wrap -> junk slots only)
                S[j - 1] = fmaf(-myc, s, S[j]);        // trailing update + rotate
                A[j - 1] = fmaf(yc, s, A[j]);          // inverse partial sums + rotate
            }
        }

        // q_i = sum_j M[i][j] mu[j]; lane = i
        const float* muk = mu + k * DIM;
        float qv = 0.f;
#pragma unroll 8
        for (int j = 0; j < DIM; ++j)
            qv = fmaf(Ylds[ln * ST + j], muk[j], qv);
        qlds[ln] = qv;

        if (ln == 0) {
            float wm = -3.0e38f;
            for (int i = 0; i < KC; ++i) wm = fmaxf(wm, w[i]);
            float se = 0.f;
            for (int i = 0; i < KC; ++i) se += __expf(w[i] - wm);
            float logw = w[k] - (wm + __logf(se));
            cstC[k] = -0.5f * (DIM * LOG_2PI + ld2) + logw - C0;
        }
    }
    __syncthreads();

    // ---- P3: emission; wave = col-tile ct. B[j][col] = M[col][j] = Ylds[col*ST+j]
    {
        const int ct = wv;
        const int col = ct * 16 + (ln & 15);
        const int kb = (ln >> 4) * 8;
#pragma unroll
        for (int kt = 0; kt < 3; ++kt) {
            short8 v;
            if (kt < 2) {
#pragma unroll
                for (int e = 0; e < 8; ++e)
                    v[e] = (short)f2bf(Ylds[col * ST + kt * 32 + kb + e]);
            } else {
#pragma unroll
                for (int e = 0; e < 8; ++e)
                    v[e] = (short)((kb + e == 0) ? f2bf(-qlds[col]) : 0);
            }
            *(short8*)(Bpack + ((size_t)(k * 12 + ct * 3 + kt) * 64 + ln) * 8) = v;
        }
    }
}

// ============================================================================
// Main: 1024 blocks x 256 thr. Block = k-subset (4 comps) x 256 rows; wave =
// 64 rows (4 row-tiles). B read DIRECT from global (L2-resident 384KB; no LDS
// staging, no barrier). Reductions via DPP on the VALU pipe. Fixed-reference
// logsumexp -> plain sums. Final scalar folded in via atomic counter.
// ============================================================================
__global__ __launch_bounds__(256, 2) void main_kernel(
    const float* __restrict__ X, const short* __restrict__ Bpack,
    const float* __restrict__ cstC, float* __restrict__ partials,
    int* __restrict__ counter, float* __restrict__ out)
{
    const int tid = threadIdx.x;
    const int lane = tid & 63;
    const int wv = tid >> 6;
    const int ks = blockIdx.x & 7;         // k in [4ks, 4ks+4)
    const int g = blockIdx.x >> 3;         // 0..127: 256-row group
    const int m = lane & 15;
    const int jb4 = (lane >> 4) * 2;       // float4 index of this lane's k-chunk

    // A fragments: 4 row-tiles x 2 K-halves, vectorized loads
    short8 a[4][2];
#pragma unroll
    for (int tt = 0; tt < 4; ++tt) {
        const float4* Xr = (const float4*)(X + (size_t)(g * 256 + wv * 64 + tt * 16 + m) * DIM);
        float4 v0 = Xr[jb4], v1 = Xr[jb4 + 1];
        float4 v2 = Xr[8 + jb4], v3 = Xr[8 + jb4 + 1];
        a[tt][0][0] = (short)f2bf(v0.x); a[tt][0][1] = (short)f2bf(v0.y);
        a[tt][0][2] = (short)f2bf(v0.z); a[tt][0][3] = (short)f2bf(v0.w);
        a[tt][0][4] = (short)f2bf(v1.x); a[tt][0][5] = (short)f2bf(v1.y);
        a[tt][0][6] = (short)f2bf(v1.z); a[tt][0][7] = (short)f2bf(v1.w);
        a[tt][1][0] = (short)f2bf(v2.x); a[tt][1][1] = (short)f2bf(v2.y);
        a[tt][1][2] = (short)f2bf(v2.z); a[tt][1][3] = (short)f2bf(v2.w);
        a[tt][1][4] = (short)f2bf(v3.x); a[tt][1][5] = (short)f2bf(v3.y);
        a[tt][1][6] = (short)f2bf(v3.z); a[tt][1][7] = (short)f2bf(v3.w);
    }
    short8 a2 = (short8)0;                 // augmented tile: x_ext[64] = 1.0
    if (lane < 16) a2[0] = (short)0x3F80;

    const short8* Bg = (const short8*)Bpack + (size_t)ks * 4 * 12 * 64;
    float acc = 0.f;
#pragma unroll
    for (int kk = 0; kk < 4; ++kk) {
        float p[4][4];
#pragma unroll
        for (int tt = 0; tt < 4; ++tt)
#pragma unroll
            for (int r = 0; r < 4; ++r) p[tt][r] = 0.f;
#pragma unroll
        for (int ct = 0; ct < 4; ++ct) {
            short8 f0 = Bg[(kk * 12 + ct * 3 + 0) * 64 + lane];
            short8 f1 = Bg[(kk * 12 + ct * 3 + 1) * 64 + lane];
            short8 f2 = Bg[(kk * 12 + ct * 3 + 2) * 64 + lane];
#pragma unroll
            for (int tt = 0; tt < 4; ++tt) {
                float4v c = {0.f, 0.f, 0.f, 0.f};
                c = __builtin_amdgcn_mfma_f32_16x16x32_bf16(a[tt][0], f0, c, 0, 0, 0);
                c = __builtin_amdgcn_mfma_f32_16x16x32_bf16(a[tt][1], f1, c, 0, 0, 0);
                c = __builtin_amdgcn_mfma_f32_16x16x32_bf16(a2, f2, c, 0, 0, 0);
                p[tt][0] = fmaf(c[0], c[0], p[tt][0]);
                p[tt][1] = fmaf(c[1], c[1], p[tt][1]);
                p[tt][2] = fmaf(c[2], c[2], p[tt][2]);
                p[tt][3] = fmaf(c[3], c[3], p[tt][3]);
            }
        }
        const float cc = cstC[ks * 4 + kk];   // wave-uniform s_load
#pragma unroll
        for (int tt = 0; tt < 4; ++tt) {
#pragma unroll
            for (int r = 0; r < 4; ++r)
                acc += __expf(fmaf(-0.5f, sum16(p[tt][r]), cc));
        }
    }
    // sum the 4 lane-groups (each group holds disjoint rows, in-group uniform)
    acc += __shfl_xor(acc, 16, 64);
    acc += __shfl_xor(acc, 32, 64);

    __shared__ float pm[4];
    __shared__ int lastdone;
    if (lane == 0) pm[wv] = acc;
    __syncthreads();
    if (tid == 0) {
        partials[blockIdx.x] = (pm[0] + pm[1]) + (pm[2] + pm[3]);
        __threadfence();                          // release partials
        lastdone = (atomicAdd(counter, 1) == 1023) ? 1 : 0;
    }
    __syncthreads();
    if (lastdone) {                               // block-uniform
        __threadfence();                          // acquire others' partials
        float s = 0.f;
        for (int i = tid; i < 1024; i += 256) s += partials[i];
#pragma unroll
        for (int mm = 1; mm <= 32; mm <<= 1) s += __shfl_xor(s, mm, 64);
        if (lane == 0) pm[wv] = s;
        __syncthreads();
        if (tid == 0) out[0] = -(C0 + logf((pm[0] + pm[1]) + (pm[2] + pm[3])));
    }
}

extern "C" void kernel_launch(void* const* d_in, const int* in_sizes, int n_in,
                              void* d_out, int out_size, void* d_ws, size_t ws_size,
                              hipStream_t stream) {
    const float* X  = (const float*)d_in[0];   // [32768,64]
    const float* mu = (const float*)d_in[1];   // [32,64]
    const float* L  = (const float*)d_in[2];   // [32,64,64]
    const float* w  = (const float*)d_in[3];   // [32]
    // d_in[4] = it (unused)

    char* ws = (char*)d_ws;
    short* Bpack   = (short*)ws;                       // 32*12*64*8 bf16 = 384 KB
    float* cstC    = (float*)(ws + 32 * 12 * 64 * 8 * 2);
    float* parts   = cstC + KC;                        // 1024 floats
    int*   counter = (int*)(parts + 1024);

    prep_kernel<<<KC, 256, 0, stream>>>(L, mu, w, Bpack, cstC, counter);
    main_kernel<<<1024, 256, 0, stream>>>(X, Bpack, cstC, parts, counter, (float*)d_out);
}

// Round 8
// 127.384 us; speedup vs baseline: 1.3771x; 1.3771x over previous
//
#include <hip/hip_runtime.h>
#include <math.h>

#define DIM 64
#define KC 32
#define NPTS 32768
#define LOG_2PI 1.8378770664093453f
#define C0 (-58.0f)   // fixed logsumexp reference: logp <= -58.81 always (logdet>=0, logw<=0)
#define ST 66         // prep LDS row stride (words): even -> 8B-aligned float2 rows

typedef __attribute__((ext_vector_type(8))) short short8;
typedef __attribute__((ext_vector_type(4))) float float4v;

__device__ __forceinline__ unsigned short f2bf(float f) {
    unsigned u = __float_as_uint(f);
    u += 0x7FFFu + ((u >> 16) & 1u);   // RNE
    return (unsigned short)(u >> 16);
}

__device__ __forceinline__ float rdlane(float v, int l) {
    return __int_as_float(__builtin_amdgcn_readlane(__float_as_int(v), l));
}

// DPP adds (VALU pipe, not LDS) — HW-verified correct in round 7.
template <int CTRL>
__device__ __forceinline__ float dpp_add(float x) {
    int t = __builtin_amdgcn_mov_dpp(__float_as_int(x), CTRL, 0xF, 0xF, true);
    return x + __int_as_float(t);
}
__device__ __forceinline__ float sum16(float x) {   // sum within each 16-lane row
    x = dpp_add<0xB1>(x);    // quad_perm [1,0,3,2]  : xor 1
    x = dpp_add<0x4E>(x);    // quad_perm [2,3,0,1]  : xor 2
    x = dpp_add<0x141>(x);   // row_half_mirror      : xor 4
    x = dpp_add<0x140>(x);   // row_mirror           : xor 8
    return x;
}

// ============================================================================
// Prep: one block (256 thr = 4 waves) per component k. r6 structure, with P2's
// two dot products SPLIT ACROSS TWO WAVES (they were serial on one wave and
// issue-bound): wave0 = Cholesky dot + column write + rd publish; wave1 =
// inverse dot (concurrent), Y-row write post-barrier. One barrier per step.
// Static full-row inner bounds backed by zero-initialized tails (exact).
// Race note: sole overlap is C[c][c] (w0 writes col c / w1 reads row c); its
// multiplier Y[c][ln] is still exactly 0, and a torn float read is still a
// finite float, so the term is exactly 0 regardless.
// Bpack[k]: 12 B-fragments: elem e of lane ln = B[kt*32+(ln>>4)*8+e][ct*16+(ln&15)],
//   B[j][i] = M[i][j] (j<64), augmented row 64 = -q. cstC[k] = cst_k - C0.
// ============================================================================
__global__ __launch_bounds__(256) void prep_kernel(
    const float* __restrict__ L, const float* __restrict__ mu,
    const float* __restrict__ w, short* __restrict__ Bpack,
    float* __restrict__ cstC)
{
    const int k = blockIdx.x;
    const int t = threadIdx.x;
    const int wv = t >> 6;
    const int ln = t & 63;
    __shared__ float Llds[DIM * ST];
    __shared__ float Sig[DIM * ST];
    __shared__ float Clds[DIM * ST];
    __shared__ float Ylds[DIM * ST];   // Ylds[j*ST + i] = M[i][j]
    __shared__ float qlds[DIM];
    __shared__ float rdbuf[DIM];
    __shared__ float ldet;

    // ---- P0: load tril(L); zero C and Y (zero tails back the static bounds)
    for (int idx = t; idx < DIM * DIM; idx += 256) {
        int r = idx >> 6, c = idx & 63;
        float v = L[(size_t)k * DIM * DIM + idx];
        Llds[r * ST + c] = (c <= r) ? v : 0.f;
    }
    for (int idx = t; idx < DIM * ST; idx += 256) {
        Clds[idx] = 0.f;
        Ylds[idx] = 0.f;
    }
    __syncthreads();

    // ---- P1: Sigma[ln][j], 16 cols per wave (tril zeros -> full sums exact)
    {
        float Lr[DIM];
        const float2* lp = (const float2*)(Llds + ln * ST);
#pragma unroll
        for (int p = 0; p < 32; ++p) {
            float2 v = lp[p];
            Lr[2 * p] = v.x; Lr[2 * p + 1] = v.y;
        }
#pragma unroll 1
        for (int jj = 0; jj < 16; ++jj) {
            const int j = wv * 16 + jj;
            const float2* up = (const float2*)(Llds + j * ST);
            float a0 = 0.f, a1 = 0.f, a2 = 0.f, a3 = 0.f;
#pragma unroll
            for (int p = 0; p < 32; p += 2) {
                float2 u0 = up[p], u1 = up[p + 1];
                a0 = fmaf(Lr[2 * p], u0.x, a0);
                a1 = fmaf(Lr[2 * p + 1], u0.y, a1);
                a2 = fmaf(Lr[2 * p + 2], u1.x, a2);
                a3 = fmaf(Lr[2 * p + 3], u1.y, a3);
            }
            float s = (a0 + a1) + (a2 + a3);
            if (j == ln) s += 1.f;
            Sig[ln * ST + j] = s;
        }
    }
    __syncthreads();

    // ---- P2: two-wave merged Cholesky + inverse, one barrier per step
    {
        const float2* crow = (const float2*)(Clds + ln * ST);   // C row ln (w0)
        const float2* yrow = (const float2*)(Ylds + ln * ST);   // M column ln (w1)
        float ld2 = 0.f;   // logdet accumulator, lives on wave 0
#pragma unroll 1
        for (int c = 0; c < DIM; ++c) {
            const float2* urow = (const float2*)(Clds + c * ST); // C row c (uniform)
            float sinv = 0.f;
            if (wv == 0) {
                float sc0 = 0.f, sc1 = 0.f;
#pragma unroll
                for (int p = 0; p < 32; ++p) {
                    float2 cu = urow[p], cr = crow[p];
                    sc0 = fmaf(cr.x, cu.x, sc0);
                    sc1 = fmaf(cr.y, cu.y, sc1);
                }
                float schol = Sig[ln * ST + c] - (sc0 + sc1);
                float d2 = rdlane(schol, c);          // trailing diagonal^2
                ld2 += __logf(d2);
                float rd = __builtin_amdgcn_rsqf(d2); // 1/C[c][c]
                Clds[ln * ST + c] = schol * rd;       // column c of C
                if (ln == 0) rdbuf[c] = rd;
            } else if (wv == 1) {
                float si0 = 0.f, si1 = 0.f;
#pragma unroll
                for (int p = 0; p < 32; ++p) {
                    float2 cu = urow[p], yr = yrow[p];
                    si0 = fmaf(yr.x, cu.x, si0);
                    si1 = fmaf(yr.y, cu.y, si1);
                }
                sinv = ((ln == c) ? 1.f : 0.f) - (si0 + si1);
            }
            __syncthreads();   // publishes C col c + rdbuf[c]
            if (wv == 1) {
                float yv = sinv * rdbuf[c];           // M[c][ln], exact all lanes
                Ylds[ln * ST + c] = (ln <= c) ? yv : 0.f;
            }
        }
        if (wv == 0 && ln == 0) ldet = ld2;
    }
    __syncthreads();   // Y complete (incl. row 63), ldet visible

    // ---- q + cst (wave 0)
    if (wv == 0) {
        const float* muk = mu + k * DIM;
        float qv = 0.f;
#pragma unroll 8
        for (int j = 0; j < DIM; ++j)
            qv = fmaf(Ylds[j * ST + ln], muk[j], qv);   // M[ln][j]
        qlds[ln] = qv;
        if (ln == 0) {
            float wm = -3.0e38f;
            for (int i = 0; i < KC; ++i) wm = fmaxf(wm, w[i]);
            float se = 0.f;
            for (int i = 0; i < KC; ++i) se += __expf(w[i] - wm);
            float logw = w[k] - (wm + __logf(se));
            cstC[k] = -0.5f * (DIM * LOG_2PI + ldet) + logw - C0;
        }
    }
    __syncthreads();

    // ---- P3: emission; wave = col-tile ct. B[j][col] = M[col][j] = Ylds[j*ST+col]
    {
        const int ct = wv;
        const int col = ct * 16 + (ln & 15);
        const int kb = (ln >> 4) * 8;
#pragma unroll
        for (int kt = 0; kt < 3; ++kt) {
            short8 v;
            if (kt < 2) {
#pragma unroll
                for (int e = 0; e < 8; ++e)
                    v[e] = (short)f2bf(Ylds[(kt * 32 + kb + e) * ST + col]);
            } else {
#pragma unroll
                for (int e = 0; e < 8; ++e)
                    v[e] = (short)((kb + e == 0) ? f2bf(-qlds[col]) : 0);
            }
            *(short8*)(Bpack + ((size_t)(k * 12 + ct * 3 + kt) * 64 + ln) * 8) = v;
        }
    }
}

// ============================================================================
// Main: r6 structure (known-good): block = k-subset (4 comps) x 128 rows;
// 2048 blocks x 256 thr; B slice (48 KB) staged once into LDS. ONLY change:
// the 16-lane reductions use DPP (VALU pipe) instead of shfl butterflies —
// removes ~130 ds_bpermute/wave from the contended LDS pipe.
// ============================================================================
__global__ __launch_bounds__(256, 2) void main_kernel(
    const float* __restrict__ X, const float* __restrict__ Bpack,
    const float* __restrict__ cstC, float* __restrict__ partials)
{
    const int tid = threadIdx.x;
    const int lane = tid & 63;
    const int wv = tid >> 6;
    const int ks = blockIdx.x & 7;         // k in [4ks, 4ks+4)
    const int g = blockIdx.x >> 3;         // row group: 128 rows

    __shared__ float4 Bsh[3072];           // 48 KB
    {
        const float4* Bg = (const float4*)Bpack + (size_t)ks * 3072;
#pragma unroll
        for (int it = 0; it < 12; ++it)
            Bsh[it * 256 + tid] = Bg[it * 256 + tid];
    }

    const int rbase = g * 128 + wv * 32;
    const int jb = (lane >> 4) * 8;
    const float* Xr0 = X + (size_t)(rbase + (lane & 15)) * DIM;
    const float* Xr1 = Xr0 + 16 * DIM;
    short8 a0, a1, b0r, b1r;
#pragma unroll
    for (int e = 0; e < 8; ++e) {
        a0[e] = (short)f2bf(Xr0[jb + e]);
        a1[e] = (short)f2bf(Xr0[32 + jb + e]);
        b0r[e] = (short)f2bf(Xr1[jb + e]);
        b1r[e] = (short)f2bf(Xr1[32 + jb + e]);
    }
    short8 a2 = (short8)0;                 // augmented tile: x_ext[64] = 1.0
    if (lane < 16) a2[0] = (short)0x3F80;

    __syncthreads();

    const short8* Bs = (const short8*)Bsh;
    float acc = 0.f;
#pragma unroll
    for (int kk = 0; kk < 4; ++kk) {
        const int k = ks * 4 + kk;
        float p0 = 0.f, p1 = 0.f, p2 = 0.f, p3 = 0.f;
        float r0 = 0.f, r1 = 0.f, r2 = 0.f, r3 = 0.f;
#pragma unroll
        for (int ct = 0; ct < 4; ++ct) {
            short8 f0 = Bs[(kk * 12 + ct * 3 + 0) * 64 + lane];
            short8 f1 = Bs[(kk * 12 + ct * 3 + 1) * 64 + lane];
            short8 f2 = Bs[(kk * 12 + ct * 3 + 2) * 64 + lane];
            float4v c0 = {0.f, 0.f, 0.f, 0.f};
            c0 = __builtin_amdgcn_mfma_f32_16x16x32_bf16(a0, f0, c0, 0, 0, 0);
            c0 = __builtin_amdgcn_mfma_f32_16x16x32_bf16(a1, f1, c0, 0, 0, 0);
            c0 = __builtin_amdgcn_mfma_f32_16x16x32_bf16(a2, f2, c0, 0, 0, 0);
            float4v c1 = {0.f, 0.f, 0.f, 0.f};
            c1 = __builtin_amdgcn_mfma_f32_16x16x32_bf16(b0r, f0, c1, 0, 0, 0);
            c1 = __builtin_amdgcn_mfma_f32_16x16x32_bf16(b1r, f1, c1, 0, 0, 0);
            c1 = __builtin_amdgcn_mfma_f32_16x16x32_bf16(a2, f2, c1, 0, 0, 0);
            p0 = fmaf(c0[0], c0[0], p0); p1 = fmaf(c0[1], c0[1], p1);
            p2 = fmaf(c0[2], c0[2], p2); p3 = fmaf(c0[3], c0[3], p3);
            r0 = fmaf(c1[0], c1[0], r0); r1 = fmaf(c1[1], c1[1], r1);
            r2 = fmaf(c1[2], c1[2], r2); r3 = fmaf(c1[3], c1[3], r3);
        }
        const float cc = cstC[k];          // wave-uniform s_load
        acc += __expf(fmaf(-0.5f, sum16(p0), cc)) + __expf(fmaf(-0.5f, sum16(p1), cc));
        acc += __expf(fmaf(-0.5f, sum16(p2), cc)) + __expf(fmaf(-0.5f, sum16(p3), cc));
        acc += __expf(fmaf(-0.5f, sum16(r0), cc)) + __expf(fmaf(-0.5f, sum16(r1), cc));
        acc += __expf(fmaf(-0.5f, sum16(r2), cc)) + __expf(fmaf(-0.5f, sum16(r3), cc));
    }
    // the 4 lane-groups hold disjoint rows (in-group duplicates after sum16)
    acc += __shfl_xor(acc, 16, 64);
    acc += __shfl_xor(acc, 32, 64);

    __shared__ float pm[4];
    if (lane == 0) pm[wv] = acc;
    __syncthreads();
    if (tid == 0)
        partials[blockIdx.x] = (pm[0] + pm[1]) + (pm[2] + pm[3]);
}

// ============================================================================
// Final: sum 2048 partials -> out = -(C0 + log(S))
// ============================================================================
__global__ __launch_bounds__(256) void final_kernel(
    const float* __restrict__ partials, int n, float* __restrict__ out)
{
    const int tid = threadIdx.x;
    float s = 0.f;
    for (int i = tid; i < n; i += 256) s += partials[i];
#pragma unroll
    for (int m = 1; m <= 32; m <<= 1) s += __shfl_xor(s, m, 64);
    __shared__ float pm[4];
    if ((tid & 63) == 0) pm[tid >> 6] = s;
    __syncthreads();
    if (tid == 0) out[0] = -(C0 + logf((pm[0] + pm[1]) + (pm[2] + pm[3])));
}

extern "C" void kernel_launch(void* const* d_in, const int* in_sizes, int n_in,
                              void* d_out, int out_size, void* d_ws, size_t ws_size,
                              hipStream_t stream) {
    const float* X  = (const float*)d_in[0];   // [32768,64]
    const float* mu = (const float*)d_in[1];   // [32,64]
    const float* L  = (const float*)d_in[2];   // [32,64,64]
    const float* w  = (const float*)d_in[3];   // [32]
    // d_in[4] = it (unused)

    char* ws = (char*)d_ws;
    short* Bpack = (short*)ws;                         // 32*12*64*8 bf16 = 384 KB
    float* cstC  = (float*)(ws + 32 * 12 * 64 * 8 * 2);
    float* parts = cstC + KC;                          // 2048 floats

    prep_kernel<<<KC, 256, 0, stream>>>(L, mu, w, Bpack, cstC);
    main_kernel<<<2048, 256, 0, stream>>>(X, (const float*)Bpack, cstC, parts);
    final_kernel<<<1, 256, 0, stream>>>(parts, 2048, (float*)d_out);
}